// Round 10
// baseline (137.706 us; speedup 1.0000x reference)
//
#include <hip/hip_runtime.h>
#include <math.h>

#define T_ 128
#define NPROJ 2176  // cols: [0,512)=Q [512,1024)=K [1024,1536)=V [1536,1600)=beta [1600,1664)=tg [1664,2176)=gate
#define CH 32       // scan chunk

typedef __attribute__((ext_vector_type(8))) short short8;
typedef __attribute__((ext_vector_type(4))) float float4v;
typedef __attribute__((ext_vector_type(2))) float float2v;

__device__ __forceinline__ ushort f2bf(float x) {
    unsigned u = __float_as_uint(x);
    u += 0x7FFF + ((u >> 16) & 1);   // RNE
    return (ushort)(u >> 16);
}
// pack two fp32 -> one dword of 2 bf16 (round-to-nearest, no tie fix)
__device__ __forceinline__ unsigned pack_bf(float a, float b) {
    unsigned ua = (__float_as_uint(a) + 0x8000u) >> 16;
    unsigned ub = (__float_as_uint(b) + 0x8000u) & 0xffff0000u;
    return ua | ub;
}
__device__ __forceinline__ float bf_lo(unsigned w) { return __uint_as_float(w << 16); }
__device__ __forceinline__ float bf_hi(unsigned w) { return __uint_as_float(w & 0xffff0000u); }

// fused DPP butterfly add: compiles to a single v_add_f32_dpp
template<int CTRL>
__device__ __forceinline__ float dpp_add(float x) {
    int xi = __float_as_int(x);
    int yi = __builtin_amdgcn_update_dpp(xi, xi, CTRL, 0xF, 0xF, false);
    return x + __int_as_float(yi);
}

// ---------------- Kernel 1: prep = params + x->bf16 + W/Wo transpose + Acomb zero -----
__global__ __launch_bounds__(256) void prep_kernel(
    const float* __restrict__ x,
    const float* __restrict__ Wq, const float* __restrict__ Wk,
    const float* __restrict__ Wv, const float* __restrict__ Wb,
    const float* __restrict__ Wtg, const float* __restrict__ Wg,
    const float* __restrict__ Wo,
    const float* __restrict__ mode_logits, const float* __restrict__ log_decay,
    const float* __restrict__ ols,
    float* __restrict__ cosw, float* __restrict__ sinw,
    float* __restrict__ rho, float* __restrict__ modew,
    ushort* __restrict__ xb, ushort* __restrict__ wtb, ushort* __restrict__ wotb,
    float* __restrict__ Acomb)
{
    __shared__ ushort tile[64][68];
    const int blk = blockIdx.x, tid = threadIdx.x;
    if (blk < 16) {
        int idx = blk * 256 + tid;
        if (idx >= 64 * 64) return;
        int t = idx >> 6;   // hr
        int k = idx & 63;
        int h = t >> 3;
        if (k == 0) {
            float ld = log_decay[t];
            rho[t] = 1.0f / (1.0f + expf(ld));  // exp(-softplus) == sigmoid(-x)
            float m = -1e30f;
            for (int i = 0; i < 8; i++) m = fmaxf(m, mode_logits[h * 8 + i]);
            float sum = 0.0f;
            for (int i = 0; i < 8; i++) sum += expf(mode_logits[h * 8 + i] - m);
            modew[t] = expf(mode_logits[t] - m) / sum;
        }
        float osc = expf(ols[t]);
        int p = k >> 1;
        float invf = expf(-((float)(2 * p) / 64.0f) * logf(10000.0f));
        float w = osc * invf;
        cosw[idx] = cosf(w);
        sinw[idx] = sinf(w);
        return;
    }
    if (blk < 80) {   // x convert
        int base = (blk - 16) * 4096 + tid * 16;
        float4 f0 = *(const float4*)&x[base];
        float4 f1 = *(const float4*)&x[base + 4];
        float4 f2 = *(const float4*)&x[base + 8];
        float4 f3 = *(const float4*)&x[base + 12];
        short8 o0, o1;
        o0[0]=f2bf(f0.x); o0[1]=f2bf(f0.y); o0[2]=f2bf(f0.z); o0[3]=f2bf(f0.w);
        o0[4]=f2bf(f1.x); o0[5]=f2bf(f1.y); o0[6]=f2bf(f1.z); o0[7]=f2bf(f1.w);
        o1[0]=f2bf(f2.x); o1[1]=f2bf(f2.y); o1[2]=f2bf(f2.z); o1[3]=f2bf(f2.w);
        o1[4]=f2bf(f3.x); o1[5]=f2bf(f3.y); o1[6]=f2bf(f3.z); o1[7]=f2bf(f3.w);
        *(short8*)&xb[base] = o0;
        *(short8*)&xb[base + 8] = o1;
        return;
    }
    if (blk >= 752) {  // zero Acomb
        int base = (blk - 752) * 4096 + tid * 16;
        float4 z = make_float4(0.f, 0.f, 0.f, 0.f);
        *(float4*)&Acomb[base] = z;
        *(float4*)&Acomb[base + 4] = z;
        *(float4*)&Acomb[base + 8] = z;
        *(float4*)&Acomb[base + 12] = z;
        return;
    }
    // transpose-convert
    const float* src; int ld, c0, n0, k0, ldd; ushort* dst;
    if (blk < 624) {
        int b3 = blk - 80; int nt = b3 >> 4, kt = b3 & 15;
        n0 = nt * 64; k0 = kt * 64;
        if (n0 < 512)       { src = Wq;  c0 = n0;        ld = 512; }
        else if (n0 < 1024) { src = Wk;  c0 = n0 - 512;  ld = 512; }
        else if (n0 < 1536) { src = Wv;  c0 = n0 - 1024; ld = 512; }
        else if (n0 < 1600) { src = Wb;  c0 = n0 - 1536; ld = 64;  }
        else if (n0 < 1664) { src = Wtg; c0 = n0 - 1600; ld = 64;  }
        else                { src = Wg;  c0 = n0 - 1664; ld = 512; }
        dst = wtb; ldd = 1024;
    } else {
        int b4 = blk - 624; int nt = b4 >> 3, kt = b4 & 7;
        n0 = nt * 64; k0 = kt * 64;
        src = Wo; c0 = n0; ld = 1024; dst = wotb; ldd = 512;
    }
    #pragma unroll
    for (int rep = 0; rep < 4; rep++) {
        int k = rep * 16 + (tid >> 4);
        int nc = (tid & 15) * 4;
        float4 f = *(const float4*)&src[(size_t)(k0 + k) * ld + c0 + nc];
        tile[nc + 0][k] = f2bf(f.x);
        tile[nc + 1][k] = f2bf(f.y);
        tile[nc + 2][k] = f2bf(f.z);
        tile[nc + 3][k] = f2bf(f.w);
    }
    __syncthreads();
    #pragma unroll
    for (int rep = 0; rep < 4; rep++) {
        int n = rep * 16 + (tid >> 4);
        int kc = (tid & 15) * 4;
        uint2 uu = *(const uint2*)&tile[n][kc];
        *(uint2*)&dst[(size_t)(n0 + n) * ldd + k0 + kc] = uu;
    }
}

// ---------------- Kernel 2: proj MFMA GEMM ---------------------------------------------
__global__ __launch_bounds__(256, 2) void proj_mfma(const ushort* __restrict__ Ab,
        const ushort* __restrict__ BTb, float* __restrict__ proj)
{
    __shared__ ushort sA[2][64][40];
    __shared__ ushort sB[2][64][40];
    const int n0 = blockIdx.x * 64, m0 = blockIdx.y * 64;
    const int tid = threadIdx.x;
    const int lane = tid & 63, w = tid >> 6;
    const int wm = w & 1, wn = w >> 1;
    const int l16 = lane & 15, quad = lane >> 4;
    const int srow = tid >> 2, skq = (tid & 3) * 8;
    const ushort* Ag = Ab + (size_t)(m0 + srow) * 1024 + skq;
    const ushort* Bg = BTb + (size_t)(n0 + srow) * 1024 + skq;
    short8 ra = *(const short8*)Ag;
    short8 rb = *(const short8*)Bg;
    float4v acc00 = {0,0,0,0}, acc01 = {0,0,0,0}, acc10 = {0,0,0,0}, acc11 = {0,0,0,0};
    for (int kt = 0; kt < 32; kt++) {
        const int cb = kt & 1;
        *(short8*)&sA[cb][srow][skq] = ra;
        *(short8*)&sB[cb][srow][skq] = rb;
        __syncthreads();
        if (kt + 1 < 32) {
            ra = *(const short8*)(Ag + (kt + 1) * 32);
            rb = *(const short8*)(Bg + (kt + 1) * 32);
        }
        short8 a0 = *(const short8*)&sA[cb][wm * 32 + l16][quad * 8];
        short8 a1 = *(const short8*)&sA[cb][wm * 32 + 16 + l16][quad * 8];
        short8 b0 = *(const short8*)&sB[cb][wn * 32 + l16][quad * 8];
        short8 b1 = *(const short8*)&sB[cb][wn * 32 + 16 + l16][quad * 8];
        acc00 = __builtin_amdgcn_mfma_f32_16x16x32_bf16(a0, b0, acc00, 0, 0, 0);
        acc01 = __builtin_amdgcn_mfma_f32_16x16x32_bf16(a0, b1, acc01, 0, 0, 0);
        acc10 = __builtin_amdgcn_mfma_f32_16x16x32_bf16(a1, b0, acc10, 0, 0, 0);
        acc11 = __builtin_amdgcn_mfma_f32_16x16x32_bf16(a1, b1, acc11, 0, 0, 0);
    }
    const bool sig = (n0 >= 1536);
    const int colb = n0 + wn * 32 + l16;
    const int rowb = m0 + wm * 32 + quad * 4;
    #pragma unroll
    for (int r2 = 0; r2 < 4; r2++) {
        float v00 = acc00[r2], v01 = acc01[r2], v10 = acc10[r2], v11 = acc11[r2];
        if (sig) {
            v00 = 1.0f / (1.0f + expf(-v00));
            v01 = 1.0f / (1.0f + expf(-v01));
            v10 = 1.0f / (1.0f + expf(-v10));
            v11 = 1.0f / (1.0f + expf(-v11));
        }
        proj[(size_t)(rowb + r2) * NPROJ + colb] = v00;
        proj[(size_t)(rowb + r2) * NPROJ + colb + 16] = v01;
        proj[(size_t)(rowb + 16 + r2) * NPROJ + colb] = v10;
        proj[(size_t)(rowb + 16 + r2) * NPROJ + colb + 16] = v11;
    }
}

// ---------------- Kernel 3: scan — bf16-packed k|q LDS (1 b128/step), reg dbuf ---------
// grid 512 = b(2) x hr(64) x s(4); block 256: vl = tid>>4 (16 v), kl = tid&15 (4 k each)
__global__ __launch_bounds__(256, 2) void scan_kernel(const float* __restrict__ proj,
        const float* __restrict__ cosw, const float* __restrict__ sinw,
        const float* __restrict__ rho, const float* __restrict__ modew,
        float* __restrict__ Acomb)
{
    __shared__ uint2 qks[2][CH][16][2];  // per (t,kl): [0]={k0..3 bf16}, [1]={q0..3}  16 KB
    __shared__ float2 vg[2][CH][16];     // {v, gate} per (t, vl)                       8 KB
    __shared__ float sc4[2][CH][4];      // [0]=beta [1]=tg [2]=kq                      1 KB
    __shared__ float obuf[CH][16];       // per-chunk outputs                           2 KB

    const int bi = blockIdx.x;
    const int s  = bi & 3;
    const int hr = (bi >> 2) & 63;
    const int b  = bi >> 8;
    const int h = hr >> 3, r = hr & 7;
    const int tid = threadIdx.x;
    const int vl = tid >> 4;             // 0..15
    const int kl = tid & 15;             // 0..15, low 4 lane bits

    float2v cw0, cw1, sw0, sw1;
    cw0.x = cosw[hr * 64 + kl * 4 + 0]; cw0.y = cosw[hr * 64 + kl * 4 + 1];
    cw1.x = cosw[hr * 64 + kl * 4 + 2]; cw1.y = cosw[hr * 64 + kl * 4 + 3];
    sw0.x = sinw[hr * 64 + kl * 4 + 0]; sw0.y = sinw[hr * 64 + kl * 4 + 1];
    sw1.x = sinw[hr * 64 + kl * 4 + 2]; sw1.y = sinw[hr * 64 + kl * 4 + 3];
    const float rho_hr = rho[hr];
    const float mw = modew[hr];
    float2v sr0 = {0,0}, sr1 = {0,0}, si0 = {0,0}, si1 = {0,0};

    const float* pb = proj + (size_t)b * T_ * NPROJ;
    const int qbase = h * 64;
    const int kbase = 512 + h * 64;
    const int vbase = 1024 + h * 64 + s * 16;
    const int gbase = 1664 + h * 64 + s * 16;
    const int boff  = 1536 + h * 8 + r;
    const int goff  = 1600 + h * 8 + r;

    // stage chunk 0 directly global->LDS (fp32 -> packed bf16 for q,k)
    {
        #pragma unroll
        for (int rep = 0; rep < 4; rep++) {
            int idx = rep * 256 + tid;
            int t = idx >> 5, sub = idx & 31;
            const float* row = pb + (size_t)t * NPROJ;
            float4 f = *(const float4*)(row + (sub < 16 ? qbase + sub * 4
                                                        : kbase + (sub - 16) * 4));
            uint2 pk2; pk2.x = pack_bf(f.x, f.y); pk2.y = pack_bf(f.z, f.w);
            qks[0][t][sub & 15][sub < 16 ? 1 : 0] = pk2;
        }
        #pragma unroll
        for (int rep = 0; rep < 2; rep++) {
            int idx = rep * 256 + tid;
            int t = idx >> 4, v2 = idx & 15;
            const float* row = pb + (size_t)t * NPROJ;
            vg[0][t][v2] = make_float2(row[vbase + v2], row[gbase + v2]);
        }
        if (tid < CH)            sc4[0][tid][0]      = pb[(size_t)tid * NPROJ + boff];
        else if (tid < 2 * CH)   sc4[0][tid - CH][1] = pb[(size_t)(tid - CH) * NPROJ + goff];
    }
    __syncthreads();

    float* dstb = Acomb + ((size_t)b * 128) * 512 + h * 64 + s * 16;

    for (int c = 0; c < T_ / CH; c++) {
        const int cb = c & 1, nb = cb ^ 1;
        const bool have = (c + 1 < T_ / CH);

        // --- global prefetch chunk c+1 into registers ---
        float4 g_qk[4]; float2 g_vg[2]; float g_sc = 0.0f;
        if (have) {
            const int t0 = (c + 1) * CH;
            #pragma unroll
            for (int rep = 0; rep < 4; rep++) {
                int idx = rep * 256 + tid;
                int t = idx >> 5, sub = idx & 31;
                const float* row = pb + (size_t)(t0 + t) * NPROJ;
                g_qk[rep] = *(const float4*)(row + (sub < 16 ? qbase + sub * 4
                                                             : kbase + (sub - 16) * 4));
            }
            #pragma unroll
            for (int rep = 0; rep < 2; rep++) {
                int idx = rep * 256 + tid;
                int t = idx >> 4, v2 = idx & 15;
                const float* row = pb + (size_t)(t0 + t) * NPROJ;
                g_vg[rep] = make_float2(row[vbase + v2], row[gbase + v2]);
            }
            if (tid < CH)          g_sc = pb[(size_t)(t0 + tid) * NPROJ + boff];
            else if (tid < 2 * CH) g_sc = pb[(size_t)(t0 + tid - CH) * NPROJ + goff];
        }

        // --- hoisted kq_t for this chunk (reads packed bf16) ---
        {
            int t = tid >> 3, j = tid & 7;
            uint4 wa = *(const uint4*)&qks[cb][t][2 * j][0];
            uint4 wb = *(const uint4*)&qks[cb][t][2 * j + 1][0];
            float p = bf_lo(wa.x) * bf_lo(wa.z) + bf_hi(wa.x) * bf_hi(wa.z)
                    + bf_lo(wa.y) * bf_lo(wa.w) + bf_hi(wa.y) * bf_hi(wa.w)
                    + bf_lo(wb.x) * bf_lo(wb.z) + bf_hi(wb.x) * bf_hi(wb.z)
                    + bf_lo(wb.y) * bf_lo(wb.w) + bf_hi(wb.y) * bf_hi(wb.w);
            p = dpp_add<0xB1>(p);   // xor1
            p = dpp_add<0x4E>(p);   // xor2
            p = dpp_add<0x141>(p);  // half-mirror within 8
            if (j == 0) sc4[cb][t][2] = p;
        }
        // --- flush previous chunk's outputs ---
        if (c > 0) {
            #pragma unroll
            for (int rep = 0; rep < 2; rep++) {
                int idx = rep * 256 + tid;
                int t = idx >> 4, v2 = idx & 15;
                atomicAdd(dstb + (size_t)((c - 1) * CH + t) * 512 + v2, obuf[t][v2]);
            }
        }
        __syncthreads();

        // --- 32 steps, single b128 k|q read per step ---
        const float2* vgb = &vg[cb][0][0];
        const float4* svb = (const float4*)&sc4[cb][0][0];

        uint4 w = *(const uint4*)&qks[cb][0][kl][0];
        float4 sv = svb[0];
        float2 vgv = vgb[vl];
        #pragma unroll
        for (int t = 0; t < CH; t++) {
            uint4 w_n; float4 sv_n; float2 vg_n;
            if (t + 1 < CH) {
                w_n = *(const uint4*)&qks[cb][t + 1][kl][0];
                sv_n = svb[t + 1];
                vg_n = vgb[(t + 1) * 16 + vl];
            }

            // unpack bf16 k|q
            float2v k0; k0.x = bf_lo(w.x); k0.y = bf_hi(w.x);
            float2v k1; k1.x = bf_lo(w.y); k1.y = bf_hi(w.y);
            float2v q0; q0.x = bf_lo(w.z); q0.y = bf_hi(w.z);
            float2v q1; q1.x = bf_lo(w.w); q1.y = bf_hi(w.w);

            const float decay = sv.y * rho_hr;
            float2v t1 = cw0 * sr0 - sw0 * si0;
            float2v u1 = sw0 * sr0 + cw0 * si0;
            float2v t2 = cw1 * sr1 - sw1 * si1;
            float2v u2 = sw1 * sr1 + cw1 * si1;
            float2v d2; d2.x = decay; d2.y = decay;
            float2v rr0 = d2 * t1, rr1 = d2 * t2;
            si0 = d2 * u1; si1 = d2 * u2;

            float2v pk2 = rr0 * k0 + rr1 * k1;
            float2v pq2 = rr0 * q0 + rr1 * q1;
            float pk = pk2.x + pk2.y;
            float pq = pq2.x + pq2.y;
            pk = dpp_add<0xB1>(pk);  pq = dpp_add<0xB1>(pq);   // xor1
            pk = dpp_add<0x4E>(pk);  pq = dpp_add<0x4E>(pq);   // xor2
            pk = dpp_add<0x141>(pk); pq = dpp_add<0x141>(pq);  // xor4
            pk = dpp_add<0x140>(pk); pq = dpp_add<0x140>(pq);  // xor8 (mirror in 16)

            const float sc = sv.x * (vgv.x - pk);
            float2v sc2; sc2.x = sc; sc2.y = sc;
            sr0 = rr0 + sc2 * k0;
            sr1 = rr1 + sc2 * k1;
            const float rp = pq + sc * sv.z;    // = sum(sr_new * q)
            if (kl == 0) obuf[t][vl] = mw * rp * vgv.y;

            w = w_n; sv = sv_n; vgv = vg_n;
        }

        // --- write staged registers into the other LDS buffer (convert to bf16) ---
        if (have) {
            #pragma unroll
            for (int rep = 0; rep < 4; rep++) {
                int idx = rep * 256 + tid;
                int t = idx >> 5, sub = idx & 31;
                float4 f = g_qk[rep];
                uint2 pk2; pk2.x = pack_bf(f.x, f.y); pk2.y = pack_bf(f.z, f.w);
                qks[nb][t][sub & 15][sub < 16 ? 1 : 0] = pk2;
            }
            #pragma unroll
            for (int rep = 0; rep < 2; rep++) {
                int idx = rep * 256 + tid;
                int t = idx >> 4, v2 = idx & 15;
                vg[nb][t][v2] = g_vg[rep];
            }
            if (tid < CH)          sc4[nb][tid][0]      = g_sc;
            else if (tid < 2 * CH) sc4[nb][tid - CH][1] = g_sc;
        }
        __syncthreads();
    }
    // final flush
    #pragma unroll
    for (int rep = 0; rep < 2; rep++) {
        int idx = rep * 256 + tid;
        int t = idx >> 4, v2 = idx & 15;
        atomicAdd(dstb + (size_t)(3 * CH + t) * 512 + v2, obuf[t][v2]);
    }
}

// ---------------- Kernel 4: output GEMM, A = fp32 Acomb converted inline ---------------
__global__ __launch_bounds__(256, 2) void out_mfma(const float* __restrict__ Af,
        const ushort* __restrict__ BTb, float* __restrict__ C)
{
    __shared__ ushort sA[2][64][40];
    __shared__ ushort sB[2][64][40];
    const int n0 = blockIdx.x * 64, m0 = blockIdx.y * 64;
    const int tid = threadIdx.x;
    const int lane = tid & 63, w = tid >> 6;
    const int wm = w & 1, wn = w >> 1;
    const int l16 = lane & 15, quad = lane >> 4;
    const int srow = tid >> 2, skq = (tid & 3) * 8;
    const float* Ag = Af + (size_t)(m0 + srow) * 512 + skq;
    const ushort* Bg = BTb + (size_t)(n0 + srow) * 512 + skq;
    float4 fa0 = *(const float4*)Ag;
    float4 fa1 = *(const float4*)(Ag + 4);
    short8 rb = *(const short8*)Bg;
    float4v acc00 = {0,0,0,0}, acc01 = {0,0,0,0}, acc10 = {0,0,0,0}, acc11 = {0,0,0,0};
    for (int kt = 0; kt < 16; kt++) {
        const int cb = kt & 1;
        short8 ra;
        ra[0]=f2bf(fa0.x); ra[1]=f2bf(fa0.y); ra[2]=f2bf(fa0.z); ra[3]=f2bf(fa0.w);
        ra[4]=f2bf(fa1.x); ra[5]=f2bf(fa1.y); ra[6]=f2bf(fa1.z); ra[7]=f2bf(fa1.w);
        *(short8*)&sA[cb][srow][skq] = ra;
        *(short8*)&sB[cb][srow][skq] = rb;
        __syncthreads();
        if (kt + 1 < 16) {
            fa0 = *(const float4*)(Ag + (kt + 1) * 32);
            fa1 = *(const float4*)(Ag + (kt + 1) * 32 + 4);
            rb = *(const short8*)(Bg + (kt + 1) * 32);
        }
        short8 a0 = *(const short8*)&sA[cb][wm * 32 + l16][quad * 8];
        short8 a1 = *(const short8*)&sA[cb][wm * 32 + 16 + l16][quad * 8];
        short8 b0 = *(const short8*)&sB[cb][wn * 32 + l16][quad * 8];
        short8 b1 = *(const short8*)&sB[cb][wn * 32 + 16 + l16][quad * 8];
        acc00 = __builtin_amdgcn_mfma_f32_16x16x32_bf16(a0, b0, acc00, 0, 0, 0);
        acc01 = __builtin_amdgcn_mfma_f32_16x16x32_bf16(a0, b1, acc01, 0, 0, 0);
        acc10 = __builtin_amdgcn_mfma_f32_16x16x32_bf16(a1, b0, acc10, 0, 0, 0);
        acc11 = __builtin_amdgcn_mfma_f32_16x16x32_bf16(a1, b1, acc11, 0, 0, 0);
    }
    const int colb = n0 + wn * 32 + l16;
    const int rowb = m0 + wm * 32 + quad * 4;
    #pragma unroll
    for (int r2 = 0; r2 < 4; r2++) {
        C[(size_t)(rowb + r2) * 1024 + colb] = acc00[r2];
        C[(size_t)(rowb + r2) * 1024 + colb + 16] = acc01[r2];
        C[(size_t)(rowb + 16 + r2) * 1024 + colb] = acc10[r2];
        C[(size_t)(rowb + 16 + r2) * 1024 + colb + 16] = acc11[r2];
    }
}

extern "C" void kernel_launch(void* const* d_in, const int* in_sizes, int n_in,
                              void* d_out, int out_size, void* d_ws, size_t ws_size,
                              hipStream_t stream) {
    const float* x   = (const float*)d_in[0];
    const float* Wq  = (const float*)d_in[1];
    const float* Wk  = (const float*)d_in[2];
    const float* Wv  = (const float*)d_in[3];
    const float* Wb  = (const float*)d_in[4];
    const float* Wtg = (const float*)d_in[5];
    const float* ml  = (const float*)d_in[6];
    const float* ldc = (const float*)d_in[7];
    const float* ols = (const float*)d_in[8];
    const float* Wg  = (const float*)d_in[9];
    const float* Wo  = (const float*)d_in[10];
    float* out = (float*)d_out;

    float* ws = (float*)d_ws;
    float* proj    = ws;                                 // 557056 f
    float* cosw    = proj + 256 * NPROJ;                 // 4096
    float* sinw    = cosw + 4096;                        // 4096
    float* rho     = sinw + 4096;                        // 64
    float* modew   = rho + 64;                           // 64
    ushort* xb     = (ushort*)(modew + 64);              // 262144 us = 131072 f
    ushort* wotb   = (ushort*)((float*)xb + 131072);     // 524288 us = 262144 f
    float*  Acomb  = (float*)wotb + 262144;              // 131072 f
    ushort* wtb    = (ushort*)(Acomb + 131072);          // 2228224 us = 1114112 f

    prep_kernel<<<784, 256, 0, stream>>>(x, Wq, Wk, Wv, Wb, Wtg, Wg, Wo,
                                         ml, ldc, ols, cosw, sinw, rho, modew,
                                         xb, wtb, wotb, Acomb);
    proj_mfma<<<dim3(34, 4), 256, 0, stream>>>(xb, wtb, proj);
    scan_kernel<<<512, 256, 0, stream>>>(proj, cosw, sinw, rho, modew, Acomb);
    out_mfma<<<dim3(16, 4), 256, 0, stream>>>(Acomb, wotb, out);
}